// Round 18
// baseline (73.560 us; speedup 1.0000x reference)
//
#include <hip/hip_runtime.h>

// Problem constants
#define B_ROWS 4096
#define DIN 64
#define NH 128
#define DOUT 512
#define ROWS_PER_BLK 16
#define MAXSTEP_CAP 1000
#define NBS 256            // solve blocks (1 per CU); prep blocks follow

typedef __attribute__((ext_vector_type(8))) short short8;
typedef __attribute__((ext_vector_type(4))) float f32x4;
typedef __attribute__((ext_vector_type(4))) unsigned u32x4;

template<int N> struct IC { static constexpr int v = N; };

// round-to-nearest-even f32 -> bf16, packed pair into a uint
__device__ inline unsigned bf16pair(float lo, float hi) {
    unsigned a = __float_as_uint(lo), b = __float_as_uint(hi);
    a = (a + 0x7fffu + ((a >> 16) & 1u)) >> 16;
    b = (b + 0x7fffu + ((b >> 16) & 1u)) >> 16;
    return a | (b << 16);
}
__device__ inline ushort bf16r(float v) {
    unsigned u = __float_as_uint(v);
    return (ushort)((u + 0x7fffu + ((u >> 16) & 1u)) >> 16);
}
__device__ inline float frcp(float x) { return __builtin_amdgcn_rcpf(x); }
__device__ inline short8 as_s8(u32x4 v) { return __builtin_bit_cast(short8, v); }

// split-at-write: v -> hi=bf16(v), lo=bf16(v-hi) (validated rounds 6-17)
__device__ inline void splitw(float v, ushort* ph, ushort* pl) {
    unsigned u = __float_as_uint(v);
    unsigned uh = (u + 0x7fffu + ((u >> 16) & 1u)) & 0xffff0000u;
    float rs = v - __uint_as_float(uh);
    unsigned ul = __float_as_uint(rs);
    *ph = (ushort)(uh >> 16);
    *pl = (ushort)((ul + 0x7fffu + ((ul >> 16) & 1u)) >> 16);
}
// split 8 gathered f32 (after relu) into hi/lo bf16 fragments
__device__ inline void packsplit8(const float* x, short8& h8, short8& l8) {
    unsigned hb[8], lb[8];
    #pragma unroll
    for (int j = 0; j < 8; ++j) {
        float v = fmaxf(x[j], 0.0f);
        unsigned u = __float_as_uint(v);
        unsigned uh = (u + 0x7fffu + ((u >> 16) & 1u)) & 0xffff0000u;
        float rs = v - __uint_as_float(uh);
        unsigned ul = __float_as_uint(rs);
        hb[j] = uh >> 16;
        lb[j] = (ul + 0x7fffu + ((ul >> 16) & 1u)) >> 16;
    }
    uint4 hv, lv;
    hv.x = hb[0] | (hb[1] << 16); hv.y = hb[2] | (hb[3] << 16);
    hv.z = hb[4] | (hb[5] << 16); hv.w = hb[6] | (hb[7] << 16);
    lv.x = lb[0] | (lb[1] << 16); lv.y = lb[2] | (lb[3] << 16);
    lv.z = lb[4] | (lb[5] << 16); lv.w = lb[6] | (lb[7] << 16);
    h8 = *reinterpret_cast<short8*>(&hv);
    l8 = *reinterpret_cast<short8*>(&lv);
}

// issue 4 global_load_dwordx4 for one wave's tile slice (4KB contiguous)
#define ISSUE_SLICE(buf, ptr) do {                                                         \
    const char* _p = (ptr);                                                                \
    asm volatile("global_load_dwordx4 %0, %1, off"             : "=v"(buf[0]) : "v"(_p));  \
    asm volatile("global_load_dwordx4 %0, %1, off offset:1024" : "=v"(buf[1]) : "v"(_p));  \
    asm volatile("global_load_dwordx4 %0, %1, off offset:2048" : "=v"(buf[2]) : "v"(_p));  \
    asm volatile("global_load_dwordx4 %0, %1, off offset:3072" : "=v"(buf[3]) : "v"(_p));  \
} while (0)

#define WAIT_VM(N) do {                                  \
    asm volatile("s_waitcnt vmcnt(" #N ")");             \
    __builtin_amdgcn_sched_barrier(0);                   \
} while (0)

// Shared-memory union for the fused solve+prep kernel (both ~34.8 KB)
struct SolveSM {
    ushort AX[2][16][136];
    ushort AY[2][16][136];
    ushort LX[2][16][136];
    ushort LY[2][16][136];
    float wred[4];
};
struct PrepSM {
    float tile[128][68];
};
#define FUSED_SM_BYTES (sizeof(SolveSM) > sizeof(PrepSM) ? sizeof(SolveSM) : sizeof(PrepSM))

// ---------------------------------------------------------------------------
// Kernel A+P (fused, round 14, validated): blocks 0..255 solve; 256..775 prep
// backfills as second-resident blocks. absmax 0.25. UNCHANGED.
// ---------------------------------------------------------------------------
__global__ __launch_bounds__(256, 1)
void solve_prep(const float* __restrict__ LT, const float* __restrict__ Kg,
                const float* __restrict__ AT, const int* __restrict__ msp,
                const float* __restrict__ ug, const float* __restrict__ eg,
                float* __restrict__ AFout, float* __restrict__ LFout,
                ushort* __restrict__ WT2)
{
    __shared__ __align__(16) unsigned char SMEM[FUSED_SM_BYTES];

    const int tid = threadIdx.x;

    if (blockIdx.x >= NBS) {
        // ================= PREP path (520 blocks) =================
        PrepSM& P = *reinterpret_cast<PrepSM*>(SMEM);
        const int bid2 = blockIdx.x - NBS;
        const int i = bid2 % 65;         // k-tile 0..64
        const int ot = bid2 / 65;        // o-tile 0..7
        const int k0 = i * 128;
        const bool mn = (i < 64);

        {
            const int r = tid >> 1, c0 = (tid & 1) * 32;
            const float* src = mn ? &ug[(size_t)(k0 + r) * DOUT + ot * 64 + c0]
                                  : &eg[(size_t)r * DOUT + ot * 64 + c0];
            const float sc = mn ? fmaxf(Kg[k0 + r], 0.0f) : 1.0f;
            #pragma unroll
            for (int g = 0; g < 8; ++g) {
                float4 v = *reinterpret_cast<const float4*>(src + g * 4);
                v.x *= sc; v.y *= sc; v.z *= sc; v.w *= sc;
                *reinterpret_cast<float4*>(&P.tile[r][c0 + g * 4]) = v;
            }
        }
        __syncthreads();
        {
            const int wnf = tid >> 4;
            const int f = wnf & 7;
            const int wn = wnf >> 3;
            const int ks = f & 3, n = (f >> 2) & 1;
            ushort* dst = WT2 + ((size_t)(ot * 65 + i) * 16 + wnf) * 512;
            #pragma unroll
            for (int q = 0; q < 4; ++q) {
                const int l = (tid & 15) * 4 + q;
                const int rb = ks * 32 + (l >> 4) * 8;
                const int c  = wn * 32 + n * 16 + (l & 15);
                uint4 v;
                v.x = bf16pair(P.tile[rb + 0][c], P.tile[rb + 1][c]);
                v.y = bf16pair(P.tile[rb + 2][c], P.tile[rb + 3][c]);
                v.z = bf16pair(P.tile[rb + 4][c], P.tile[rb + 5][c]);
                v.w = bf16pair(P.tile[rb + 6][c], P.tile[rb + 7][c]);
                *reinterpret_cast<uint4*>(dst + l * 8) = v;
            }
        }
        return;
    }

    // ================= SOLVE path (blocks 0..255) =================
    SolveSM& S = *reinterpret_cast<SolveSM*>(SMEM);
    auto& AX = S.AX; auto& AY = S.AY; auto& LX = S.LX; auto& LY = S.LY;
    auto& wred = S.wred;

    const int lane = tid & 63, w = tid >> 6;
    const int lr = lane & 15, lg = lane >> 4;
    const int b0row = blockIdx.x * ROWS_PER_BLK;

    for (int idx = tid; idx < 2176; idx += 256) {
        reinterpret_cast<unsigned*>(&AX[0][0][0])[idx] = 0u;
        reinterpret_cast<unsigned*>(&LX[0][0][0])[idx] = 0u;
    }

    int max_step = *msp;
    if (max_step > MAXSTEP_CAP) max_step = MAXSTEP_CAP;

    short8 BkH[4], BkL[4];
    #pragma unroll
    for (int ks = 0; ks < 4; ++ks) {
        float xx[8];
        const float* p = &Kg[(16 * w + lr) * NH + ks * 32 + lg * 8];
        #pragma unroll
        for (int j = 0; j < 8; ++j) xx[j] = p[j];
        packsplit8(xx, BkH[ks], BkL[ks]);
    }
    short8 BtH[2][2], BtL[2][2];
    #pragma unroll
    for (int t = 0; t < 2; ++t)
        #pragma unroll
        for (int ks = 0; ks < 2; ++ks) {
            float xx[8];
            #pragma unroll
            for (int j = 0; j < 8; ++j)
                xx[j] = Kg[(ks * 32 + lg * 8 + j) * NH + 32 * w + 16 * t + lr];
            packsplit8(xx, BtH[t][ks], BtL[t][ks]);
        }

    float ltv[4];
    #pragma unroll
    for (int r = 0; r < 4; ++r)
        ltv[r] = LT[(size_t)(b0row + lg * 4 + r) * DIN + 16 * w + lr];
    float atv[2];
    #pragma unroll
    for (int t = 0; t < 2; ++t)
        atv[t] = fmaxf(AT[32 * w + 16 * t + lr], 0.f);

    float prevA[2][4] = {};
    float prevL[4] = {};
    bool done = false;

    __syncthreads();

    auto iterate = [&](auto MC, bool check, float tol) {
        constexpr int mode = decltype(MC)::v;
        {   // AF P1
            f32x4 aH = {0.f,0.f,0.f,0.f}, aL = aH;
            #pragma unroll
            for (int ks = 0; ks < 4; ++ks) {
                short8 hi = *reinterpret_cast<const short8*>(&AX[0][lr][ks * 32 + lg * 8]);
                aH = __builtin_amdgcn_mfma_f32_16x16x32_bf16(hi, BkH[ks], aH, 0, 0, 0);
                if (mode >= 1) {
                    short8 lo = *reinterpret_cast<const short8*>(&AX[1][lr][ks * 32 + lg * 8]);
                    aL = __builtin_amdgcn_mfma_f32_16x16x32_bf16(lo, BkH[ks], aL, 0, 0, 0);
                }
                if (mode == 2)
                    aL = __builtin_amdgcn_mfma_f32_16x16x32_bf16(hi, BkL[ks], aL, 0, 0, 0);
            }
            #pragma unroll
            for (int r = 0; r < 4; ++r) {
                float v = ltv[r] * frcp(aH[r] + aL[r] + 1.0f);
                if (mode == 0) AY[0][lg * 4 + r][16 * w + lr] = bf16r(v);
                else splitw(v, &AY[0][lg * 4 + r][16 * w + lr],
                               &AY[1][lg * 4 + r][16 * w + lr]);
            }
        }
        {   // LF P1
            short8 xh0 = *reinterpret_cast<const short8*>(&LX[0][lr][lg * 8]);
            short8 xh1 = *reinterpret_cast<const short8*>(&LX[0][lr][32 + lg * 8]);
            short8 xl0, xl1;
            if (mode >= 1) {
                xl0 = *reinterpret_cast<const short8*>(&LX[1][lr][lg * 8]);
                xl1 = *reinterpret_cast<const short8*>(&LX[1][lr][32 + lg * 8]);
            }
            #pragma unroll
            for (int t = 0; t < 2; ++t) {
                f32x4 bH = {0.f,0.f,0.f,0.f}, bL = bH;
                bH = __builtin_amdgcn_mfma_f32_16x16x32_bf16(xh0, BtH[t][0], bH, 0, 0, 0);
                bH = __builtin_amdgcn_mfma_f32_16x16x32_bf16(xh1, BtH[t][1], bH, 0, 0, 0);
                if (mode >= 1) {
                    bL = __builtin_amdgcn_mfma_f32_16x16x32_bf16(xl0, BtH[t][0], bL, 0, 0, 0);
                    bL = __builtin_amdgcn_mfma_f32_16x16x32_bf16(xl1, BtH[t][1], bL, 0, 0, 0);
                }
                if (mode == 2) {
                    bL = __builtin_amdgcn_mfma_f32_16x16x32_bf16(xh0, BtL[t][0], bL, 0, 0, 0);
                    bL = __builtin_amdgcn_mfma_f32_16x16x32_bf16(xh1, BtL[t][1], bL, 0, 0, 0);
                }
                #pragma unroll
                for (int r = 0; r < 4; ++r) {
                    float v = atv[t] * frcp(bH[r] + bL[r] + 1.0f);
                    if (mode == 0) LY[0][lg * 4 + r][32 * w + 16 * t + lr] = bf16r(v);
                    else splitw(v, &LY[0][lg * 4 + r][32 * w + 16 * t + lr],
                                   &LY[1][lg * 4 + r][32 * w + 16 * t + lr]);
                }
            }
        }
        __syncthreads();
        float flag = -1.0f;
        {   // AF P2
            short8 yh0 = *reinterpret_cast<const short8*>(&AY[0][lr][lg * 8]);
            short8 yh1 = *reinterpret_cast<const short8*>(&AY[0][lr][32 + lg * 8]);
            short8 yl0, yl1;
            if (mode >= 1) {
                yl0 = *reinterpret_cast<const short8*>(&AY[1][lr][lg * 8]);
                yl1 = *reinterpret_cast<const short8*>(&AY[1][lr][32 + lg * 8]);
            }
            #pragma unroll
            for (int t = 0; t < 2; ++t) {
                f32x4 bH = {0.f,0.f,0.f,0.f}, bL = bH;
                bH = __builtin_amdgcn_mfma_f32_16x16x32_bf16(yh0, BtH[t][0], bH, 0, 0, 0);
                bH = __builtin_amdgcn_mfma_f32_16x16x32_bf16(yh1, BtH[t][1], bH, 0, 0, 0);
                if (mode >= 1) {
                    bL = __builtin_amdgcn_mfma_f32_16x16x32_bf16(yl0, BtH[t][0], bL, 0, 0, 0);
                    bL = __builtin_amdgcn_mfma_f32_16x16x32_bf16(yl1, BtH[t][1], bL, 0, 0, 0);
                }
                if (mode == 2) {
                    bL = __builtin_amdgcn_mfma_f32_16x16x32_bf16(yh0, BtL[t][0], bL, 0, 0, 0);
                    bL = __builtin_amdgcn_mfma_f32_16x16x32_bf16(yh1, BtL[t][1], bL, 0, 0, 0);
                }
                #pragma unroll
                for (int r = 0; r < 4; ++r) {
                    float v = atv[t] * frcp(bH[r] + bL[r] + 1.0f);
                    if (check) {
                        float p = prevA[t][r];
                        flag = fmaxf(flag, fabsf(v - p) - tol * (p + 1e-5f));
                    }
                    prevA[t][r] = v;
                    if (mode == 0) AX[0][lg * 4 + r][32 * w + 16 * t + lr] = bf16r(v);
                    else splitw(v, &AX[0][lg * 4 + r][32 * w + 16 * t + lr],
                                   &AX[1][lg * 4 + r][32 * w + 16 * t + lr]);
                }
            }
        }
        {   // LF P2
            f32x4 aH = {0.f,0.f,0.f,0.f}, aL = aH;
            #pragma unroll
            for (int ks = 0; ks < 4; ++ks) {
                short8 hi = *reinterpret_cast<const short8*>(&LY[0][lr][ks * 32 + lg * 8]);
                aH = __builtin_amdgcn_mfma_f32_16x16x32_bf16(hi, BkH[ks], aH, 0, 0, 0);
                if (mode >= 1) {
                    short8 lo = *reinterpret_cast<const short8*>(&LY[1][lr][ks * 32 + lg * 8]);
                    aL = __builtin_amdgcn_mfma_f32_16x16x32_bf16(lo, BkH[ks], aL, 0, 0, 0);
                }
                if (mode == 2)
                    aL = __builtin_amdgcn_mfma_f32_16x16x32_bf16(hi, BkL[ks], aL, 0, 0, 0);
            }
            #pragma unroll
            for (int r = 0; r < 4; ++r) {
                float v = ltv[r] * frcp(aH[r] + aL[r] + 1.0f);
                if (check) {
                    float p = prevL[r];
                    flag = fmaxf(flag, fabsf(v - p) - tol * (p + 1e-5f));
                }
                prevL[r] = v;
                if (mode == 0) LX[0][lg * 4 + r][16 * w + lr] = bf16r(v);
                else splitw(v, &LX[0][lg * 4 + r][16 * w + lr],
                               &LX[1][lg * 4 + r][16 * w + lr]);
            }
        }
        if (check) {
            #pragma unroll
            for (int off = 32; off; off >>= 1)
                flag = fmaxf(flag, __shfl_xor(flag, off));
            if (lane == 0) wred[w] = flag;
        }
        __syncthreads();
        if (check)
            done = fmaxf(fmaxf(wred[0], wred[1]), fmaxf(wred[2], wred[3])) < 0.0f;
    };

    int step = 0;
    const int cheapN = max_step < 12 ? max_step : 12;
    for (int s = 0; s < cheapN; ++s, ++step)
        iterate(IC<0>{}, false, 0.f);
    const int capC = max_step < 64 ? max_step : 64;
    while (step < capC && !done) { iterate(IC<0>{}, true, 6e-3f); ++step; }
    done = false;
    while (step < max_step && !done) { iterate(IC<1>{}, true, 5e-5f); ++step; }
    iterate(IC<2>{}, false, 0.f);
    iterate(IC<2>{}, false, 0.f);
    iterate(IC<2>{}, false, 0.f);

    #pragma unroll
    for (int t = 0; t < 2; ++t)
        #pragma unroll
        for (int r = 0; r < 4; ++r)
            AFout[(size_t)(b0row + lg * 4 + r) * NH + 32 * w + 16 * t + lr] = prevA[t][r];
    #pragma unroll
    for (int r = 0; r < 4; ++r)
        LFout[(size_t)(b0row + lg * 4 + r) * DIN + 16 * w + lr] = prevL[r];
}

// ---------------------------------------------------------------------------
// Kernel B (v12): round-17 GEMM (64-row tile, 2 blocks/CU, co-residency
// o-tile remap) with the pipeline deepened 3 -> 4 buffers on the SLICE
// structure (only 64 tied VGPRs — vs r11's 128-tied corruption / r15's
// 80-tied crash on fatter layouts; total ~200 < 256 cap). Steady state:
// 4 tiles (16 loads) in flight, WAIT_VM(12) = oldest resident + 3 flying
// (~360cy+). Tail hand-verified: 16 outstanding -> 12/12/12/12/12 -> 8/4/0.
// Fallback pre-committed: crash/absmax-shift => revert to r17, declare.
// ---------------------------------------------------------------------------
__global__ __launch_bounds__(256, 2)
void out_gemm_rank1(const float* __restrict__ AFw, const float* __restrict__ LFw,
                    const ushort* __restrict__ WT2, const float* __restrict__ bg,
                    float* __restrict__ out)
{
    __shared__ __align__(16) ushort AFb[64][136];
    __shared__ __align__(16) float  LFt[64][68];

    const int t = threadIdx.x;
    const int ot = (blockIdx.x & 255) >> 5;
    const int b0 = ((blockIdx.x >> 8) * 32 + (blockIdx.x & 31)) * 64;
    const int o0 = ot * 64;
    const int w = t >> 6, l = t & 63;
    const int lr = l & 15, lg = l >> 4;

    {
        const int row = t >> 2, q = t & 3;
        const float4* srcA = reinterpret_cast<const float4*>(
            &AFw[(size_t)(b0 + row) * NH + q * 32]);
        #pragma unroll
        for (int g = 0; g < 4; ++g) {
            float4 fa = srcA[2 * g], fb = srcA[2 * g + 1];
            uint4 wv;
            wv.x = bf16pair(fa.x, fa.y); wv.y = bf16pair(fa.z, fa.w);
            wv.z = bf16pair(fb.x, fb.y); wv.w = bf16pair(fb.z, fb.w);
            *reinterpret_cast<uint4*>(&AFb[row][q * 32 + g * 8]) = wv;
        }
        const f32x4* srcL = reinterpret_cast<const f32x4*>(
            &LFw[(size_t)(b0 + row) * DIN + q * 16]);
        #pragma unroll
        for (int g = 0; g < 4; ++g) {
            f32x4 fv = srcL[g];
            #pragma unroll
            for (int j = 0; j < 4; ++j)
                LFt[q * 16 + g * 4 + j][row] = fv[j];
        }
    }
    __syncthreads();

    const char* base = reinterpret_cast<const char*>(WT2)
        + ((size_t)(ot * 65) * 16) * 1024 + w * 4096 + l * 16;

    u32x4 bf0[4], bf1[4], bf2[4], bf3[4];
    ISSUE_SLICE(bf0, base);                      // T0
    ISSUE_SLICE(bf1, base + 16384);              // T1
    ISSUE_SLICE(bf2, base + 2 * 16384);          // T2
    ISSUE_SLICE(bf3, base + 3 * 16384);          // T3

    short8 afr[4][4];
    #pragma unroll
    for (int m = 0; m < 4; ++m)
        #pragma unroll
        for (int ks = 0; ks < 4; ++ks)
            afr[m][ks] = *reinterpret_cast<const short8*>(
                &AFb[m * 16 + lr][ks * 32 + lg * 8]);

    f32x4 acc[4], tt[4];
    #pragma unroll
    for (int m = 0; m < 4; ++m) acc[m] = (f32x4){0.f, 0.f, 0.f, 0.f};

    auto computeI = [&](const u32x4* bf) {
        #pragma unroll
        for (int m = 0; m < 4; ++m) tt[m] = (f32x4){0.f, 0.f, 0.f, 0.f};
        __builtin_amdgcn_s_setprio(1);
        #pragma unroll
        for (int ks = 0; ks < 4; ++ks) {
            short8 bv = as_s8(bf[ks]);
            #pragma unroll
            for (int m = 0; m < 4; ++m)
                tt[m] = __builtin_amdgcn_mfma_f32_16x16x32_bf16(afr[m][ks], bv, tt[m], 0, 0, 0);
        }
        __builtin_amdgcn_s_setprio(0);
    };
    auto scaleAdd = [&](int i) {
        #pragma unroll
        for (int m = 0; m < 4; ++m) {
            f32x4 lf = *reinterpret_cast<const f32x4*>(&LFt[i][m * 16 + lg * 4]);
            #pragma unroll
            for (int r = 0; r < 4; ++r)
                acc[m][r] += lf[r] * tt[m][r];
        }
    };

    // tiles 0..64. Steady state: 4 tiles (16 loads) in flight;
    // WAIT_VM(12) == oldest tile resident, 3 tiles (~360cy+) still flying.
    #pragma unroll 1
    for (int i = 0; i < 56; i += 4) {
        const char* p = base + (size_t)(i + 4) * 16384;
        WAIT_VM(12); computeI(bf0); scaleAdd(i);     ISSUE_SLICE(bf0, p);
        WAIT_VM(12); computeI(bf1); scaleAdd(i + 1); ISSUE_SLICE(bf1, p + 16384);
        WAIT_VM(12); computeI(bf2); scaleAdd(i + 2); ISSUE_SLICE(bf2, p + 2 * 16384);
        WAIT_VM(12); computeI(bf3); scaleAdd(i + 3); ISSUE_SLICE(bf3, p + 3 * 16384);
    }
    // computed T0..T55; outstanding: T56(bf0),T57(bf1),T58(bf2),T59(bf3)
    WAIT_VM(12); computeI(bf0); scaleAdd(56); ISSUE_SLICE(bf0, base + (size_t)60 * 16384);
    WAIT_VM(12); computeI(bf1); scaleAdd(57); ISSUE_SLICE(bf1, base + (size_t)61 * 16384);
    WAIT_VM(12); computeI(bf2); scaleAdd(58); ISSUE_SLICE(bf2, base + (size_t)62 * 16384);
    WAIT_VM(12); computeI(bf3); scaleAdd(59); ISSUE_SLICE(bf3, base + (size_t)63 * 16384);
    WAIT_VM(12); computeI(bf0); scaleAdd(60); ISSUE_SLICE(bf0, base + (size_t)64 * 16384);
    WAIT_VM(12); computeI(bf1); scaleAdd(61);
    WAIT_VM(8);  computeI(bf2); scaleAdd(62);
    WAIT_VM(4);  computeI(bf3); scaleAdd(63);
    WAIT_VM(0);  computeI(bf0);                  // T64: e-term, scale 1
    #pragma unroll
    for (int m = 0; m < 4; ++m)
        #pragma unroll
        for (int r = 0; r < 4; ++r)
            acc[m][r] += tt[m][r];

    const int col = o0 + w * 16 + lr;
    const float bb = bg[col];
    #pragma unroll
    for (int m = 0; m < 4; ++m) {
        #pragma unroll
        for (int r = 0; r < 4; ++r) {
            const int row = b0 + m * 16 + lg * 4 + r;
            out[(size_t)row * DOUT + col] = acc[m][r] + bb;
        }
    }
}

// ---------------------------------------------------------------------------
// Workspace layout (bytes):
//   [0,        2097152)   AF  : float[4096][128]
//   [2097152,  3145728)   LF  : float[4096][64]
//   [3145728, +8519680)   WT2 : fragment-ordered bf16 W (8 o-tiles x 65 x 16KB)
// Fully rewritten before use each launch -> deterministic.
// ---------------------------------------------------------------------------
extern "C" void kernel_launch(void* const* d_in, const int* in_sizes, int n_in,
                              void* d_out, int out_size, void* d_ws, size_t ws_size,
                              hipStream_t stream)
{
    const float* LT   = (const float*)d_in[0];
    const float* Kg   = (const float*)d_in[1];
    const float* AT   = (const float*)d_in[2];
    const float* ug   = (const float*)d_in[3];
    const float* eg   = (const float*)d_in[4];
    const float* bg   = (const float*)d_in[5];
    const int*   msp  = (const int*)d_in[6];
    float* out = (float*)d_out;

    char* ws = (char*)d_ws;
    float*  AFw = (float*)(ws);
    float*  LFw = (float*)(ws + 2097152);
    ushort* WT2 = (ushort*)(ws + 3145728);

    // fused: 256 solve blocks + 520 prep blocks (prep hides under solve)
    solve_prep<<<dim3(NBS + 520), dim3(256), 0, stream>>>(
        LT, Kg, AT, msp, ug, eg, AFw, LFw, WT2);

    out_gemm_rank1<<<dim3(512), dim3(256), 0, stream>>>(AFw, LFw, WT2, bg, out);
}

// Round 19
// 67.164 us; speedup vs baseline: 1.0952x; 1.0952x over previous
//
#include <hip/hip_runtime.h>

// Problem constants
#define B_ROWS 4096
#define DIN 64
#define NH 128
#define DOUT 512
#define ROWS_PER_BLK 16
#define MAXSTEP_CAP 1000
#define NBS 256            // solve blocks (1 per CU); prep blocks follow

typedef __attribute__((ext_vector_type(8))) short short8;
typedef __attribute__((ext_vector_type(4))) float f32x4;
typedef __attribute__((ext_vector_type(4))) unsigned u32x4;

template<int N> struct IC { static constexpr int v = N; };

// round-to-nearest-even f32 -> bf16, packed pair into a uint
__device__ inline unsigned bf16pair(float lo, float hi) {
    unsigned a = __float_as_uint(lo), b = __float_as_uint(hi);
    a = (a + 0x7fffu + ((a >> 16) & 1u)) >> 16;
    b = (b + 0x7fffu + ((b >> 16) & 1u)) >> 16;
    return a | (b << 16);
}
__device__ inline ushort bf16r(float v) {
    unsigned u = __float_as_uint(v);
    return (ushort)((u + 0x7fffu + ((u >> 16) & 1u)) >> 16);
}
__device__ inline float frcp(float x) { return __builtin_amdgcn_rcpf(x); }
__device__ inline short8 as_s8(u32x4 v) { return __builtin_bit_cast(short8, v); }

// split-at-write: v -> hi=bf16(v), lo=bf16(v-hi) (validated rounds 6-17)
__device__ inline void splitw(float v, ushort* ph, ushort* pl) {
    unsigned u = __float_as_uint(v);
    unsigned uh = (u + 0x7fffu + ((u >> 16) & 1u)) & 0xffff0000u;
    float rs = v - __uint_as_float(uh);
    unsigned ul = __float_as_uint(rs);
    *ph = (ushort)(uh >> 16);
    *pl = (ushort)((ul + 0x7fffu + ((ul >> 16) & 1u)) >> 16);
}
// split 8 gathered f32 (after relu) into hi/lo bf16 fragments
__device__ inline void packsplit8(const float* x, short8& h8, short8& l8) {
    unsigned hb[8], lb[8];
    #pragma unroll
    for (int j = 0; j < 8; ++j) {
        float v = fmaxf(x[j], 0.0f);
        unsigned u = __float_as_uint(v);
        unsigned uh = (u + 0x7fffu + ((u >> 16) & 1u)) & 0xffff0000u;
        float rs = v - __uint_as_float(uh);
        unsigned ul = __float_as_uint(rs);
        hb[j] = uh >> 16;
        lb[j] = (ul + 0x7fffu + ((ul >> 16) & 1u)) >> 16;
    }
    uint4 hv, lv;
    hv.x = hb[0] | (hb[1] << 16); hv.y = hb[2] | (hb[3] << 16);
    hv.z = hb[4] | (hb[5] << 16); hv.w = hb[6] | (hb[7] << 16);
    lv.x = lb[0] | (lb[1] << 16); lv.y = lb[2] | (lb[3] << 16);
    lv.z = lb[4] | (lb[5] << 16); lv.w = lb[6] | (lb[7] << 16);
    h8 = *reinterpret_cast<short8*>(&hv);
    l8 = *reinterpret_cast<short8*>(&lv);
}

// issue 4 global_load_dwordx4 for one wave's tile slice (4KB contiguous)
#define ISSUE_SLICE(buf, ptr) do {                                                         \
    const char* _p = (ptr);                                                                \
    asm volatile("global_load_dwordx4 %0, %1, off"             : "=v"(buf[0]) : "v"(_p));  \
    asm volatile("global_load_dwordx4 %0, %1, off offset:1024" : "=v"(buf[1]) : "v"(_p));  \
    asm volatile("global_load_dwordx4 %0, %1, off offset:2048" : "=v"(buf[2]) : "v"(_p));  \
    asm volatile("global_load_dwordx4 %0, %1, off offset:3072" : "=v"(buf[3]) : "v"(_p));  \
} while (0)

#define WAIT_VM(N) do {                                  \
    asm volatile("s_waitcnt vmcnt(" #N ")");             \
    __builtin_amdgcn_sched_barrier(0);                   \
} while (0)

// Shared-memory union for the fused solve+prep kernel (both ~34.8 KB)
struct SolveSM {
    ushort AX[2][16][136];
    ushort AY[2][16][136];
    ushort LX[2][16][136];
    ushort LY[2][16][136];
    float wred[4];
};
struct PrepSM {
    float tile[128][68];
};
#define FUSED_SM_BYTES (sizeof(SolveSM) > sizeof(PrepSM) ? sizeof(SolveSM) : sizeof(PrepSM))

// ---------------------------------------------------------------------------
// Kernel A+P (fused, round 14, validated): blocks 0..255 solve; 256..775 prep
// backfills as second-resident blocks. absmax 0.25. UNCHANGED.
// ---------------------------------------------------------------------------
__global__ __launch_bounds__(256, 1)
void solve_prep(const float* __restrict__ LT, const float* __restrict__ Kg,
                const float* __restrict__ AT, const int* __restrict__ msp,
                const float* __restrict__ ug, const float* __restrict__ eg,
                float* __restrict__ AFout, float* __restrict__ LFout,
                ushort* __restrict__ WT2)
{
    __shared__ __align__(16) unsigned char SMEM[FUSED_SM_BYTES];

    const int tid = threadIdx.x;

    if (blockIdx.x >= NBS) {
        // ================= PREP path (520 blocks) =================
        PrepSM& P = *reinterpret_cast<PrepSM*>(SMEM);
        const int bid2 = blockIdx.x - NBS;
        const int i = bid2 % 65;         // k-tile 0..64
        const int ot = bid2 / 65;        // o-tile 0..7
        const int k0 = i * 128;
        const bool mn = (i < 64);

        {
            const int r = tid >> 1, c0 = (tid & 1) * 32;
            const float* src = mn ? &ug[(size_t)(k0 + r) * DOUT + ot * 64 + c0]
                                  : &eg[(size_t)r * DOUT + ot * 64 + c0];
            const float sc = mn ? fmaxf(Kg[k0 + r], 0.0f) : 1.0f;
            #pragma unroll
            for (int g = 0; g < 8; ++g) {
                float4 v = *reinterpret_cast<const float4*>(src + g * 4);
                v.x *= sc; v.y *= sc; v.z *= sc; v.w *= sc;
                *reinterpret_cast<float4*>(&P.tile[r][c0 + g * 4]) = v;
            }
        }
        __syncthreads();
        {
            const int wnf = tid >> 4;
            const int f = wnf & 7;
            const int wn = wnf >> 3;
            const int ks = f & 3, n = (f >> 2) & 1;
            ushort* dst = WT2 + ((size_t)(ot * 65 + i) * 16 + wnf) * 512;
            #pragma unroll
            for (int q = 0; q < 4; ++q) {
                const int l = (tid & 15) * 4 + q;
                const int rb = ks * 32 + (l >> 4) * 8;
                const int c  = wn * 32 + n * 16 + (l & 15);
                uint4 v;
                v.x = bf16pair(P.tile[rb + 0][c], P.tile[rb + 1][c]);
                v.y = bf16pair(P.tile[rb + 2][c], P.tile[rb + 3][c]);
                v.z = bf16pair(P.tile[rb + 4][c], P.tile[rb + 5][c]);
                v.w = bf16pair(P.tile[rb + 6][c], P.tile[rb + 7][c]);
                *reinterpret_cast<uint4*>(dst + l * 8) = v;
            }
        }
        return;
    }

    // ================= SOLVE path (blocks 0..255) =================
    SolveSM& S = *reinterpret_cast<SolveSM*>(SMEM);
    auto& AX = S.AX; auto& AY = S.AY; auto& LX = S.LX; auto& LY = S.LY;
    auto& wred = S.wred;

    const int lane = tid & 63, w = tid >> 6;
    const int lr = lane & 15, lg = lane >> 4;
    const int b0row = blockIdx.x * ROWS_PER_BLK;

    for (int idx = tid; idx < 2176; idx += 256) {
        reinterpret_cast<unsigned*>(&AX[0][0][0])[idx] = 0u;
        reinterpret_cast<unsigned*>(&LX[0][0][0])[idx] = 0u;
    }

    int max_step = *msp;
    if (max_step > MAXSTEP_CAP) max_step = MAXSTEP_CAP;

    short8 BkH[4], BkL[4];
    #pragma unroll
    for (int ks = 0; ks < 4; ++ks) {
        float xx[8];
        const float* p = &Kg[(16 * w + lr) * NH + ks * 32 + lg * 8];
        #pragma unroll
        for (int j = 0; j < 8; ++j) xx[j] = p[j];
        packsplit8(xx, BkH[ks], BkL[ks]);
    }
    short8 BtH[2][2], BtL[2][2];
    #pragma unroll
    for (int t = 0; t < 2; ++t)
        #pragma unroll
        for (int ks = 0; ks < 2; ++ks) {
            float xx[8];
            #pragma unroll
            for (int j = 0; j < 8; ++j)
                xx[j] = Kg[(ks * 32 + lg * 8 + j) * NH + 32 * w + 16 * t + lr];
            packsplit8(xx, BtH[t][ks], BtL[t][ks]);
        }

    float ltv[4];
    #pragma unroll
    for (int r = 0; r < 4; ++r)
        ltv[r] = LT[(size_t)(b0row + lg * 4 + r) * DIN + 16 * w + lr];
    float atv[2];
    #pragma unroll
    for (int t = 0; t < 2; ++t)
        atv[t] = fmaxf(AT[32 * w + 16 * t + lr], 0.f);

    float prevA[2][4] = {};
    float prevL[4] = {};
    bool done = false;

    __syncthreads();

    auto iterate = [&](auto MC, bool check, float tol) {
        constexpr int mode = decltype(MC)::v;
        {   // AF P1
            f32x4 aH = {0.f,0.f,0.f,0.f}, aL = aH;
            #pragma unroll
            for (int ks = 0; ks < 4; ++ks) {
                short8 hi = *reinterpret_cast<const short8*>(&AX[0][lr][ks * 32 + lg * 8]);
                aH = __builtin_amdgcn_mfma_f32_16x16x32_bf16(hi, BkH[ks], aH, 0, 0, 0);
                if (mode >= 1) {
                    short8 lo = *reinterpret_cast<const short8*>(&AX[1][lr][ks * 32 + lg * 8]);
                    aL = __builtin_amdgcn_mfma_f32_16x16x32_bf16(lo, BkH[ks], aL, 0, 0, 0);
                }
                if (mode == 2)
                    aL = __builtin_amdgcn_mfma_f32_16x16x32_bf16(hi, BkL[ks], aL, 0, 0, 0);
            }
            #pragma unroll
            for (int r = 0; r < 4; ++r) {
                float v = ltv[r] * frcp(aH[r] + aL[r] + 1.0f);
                if (mode == 0) AY[0][lg * 4 + r][16 * w + lr] = bf16r(v);
                else splitw(v, &AY[0][lg * 4 + r][16 * w + lr],
                               &AY[1][lg * 4 + r][16 * w + lr]);
            }
        }
        {   // LF P1
            short8 xh0 = *reinterpret_cast<const short8*>(&LX[0][lr][lg * 8]);
            short8 xh1 = *reinterpret_cast<const short8*>(&LX[0][lr][32 + lg * 8]);
            short8 xl0, xl1;
            if (mode >= 1) {
                xl0 = *reinterpret_cast<const short8*>(&LX[1][lr][lg * 8]);
                xl1 = *reinterpret_cast<const short8*>(&LX[1][lr][32 + lg * 8]);
            }
            #pragma unroll
            for (int t = 0; t < 2; ++t) {
                f32x4 bH = {0.f,0.f,0.f,0.f}, bL = bH;
                bH = __builtin_amdgcn_mfma_f32_16x16x32_bf16(xh0, BtH[t][0], bH, 0, 0, 0);
                bH = __builtin_amdgcn_mfma_f32_16x16x32_bf16(xh1, BtH[t][1], bH, 0, 0, 0);
                if (mode >= 1) {
                    bL = __builtin_amdgcn_mfma_f32_16x16x32_bf16(xl0, BtH[t][0], bL, 0, 0, 0);
                    bL = __builtin_amdgcn_mfma_f32_16x16x32_bf16(xl1, BtH[t][1], bL, 0, 0, 0);
                }
                if (mode == 2) {
                    bL = __builtin_amdgcn_mfma_f32_16x16x32_bf16(xh0, BtL[t][0], bL, 0, 0, 0);
                    bL = __builtin_amdgcn_mfma_f32_16x16x32_bf16(xh1, BtL[t][1], bL, 0, 0, 0);
                }
                #pragma unroll
                for (int r = 0; r < 4; ++r) {
                    float v = atv[t] * frcp(bH[r] + bL[r] + 1.0f);
                    if (mode == 0) LY[0][lg * 4 + r][32 * w + 16 * t + lr] = bf16r(v);
                    else splitw(v, &LY[0][lg * 4 + r][32 * w + 16 * t + lr],
                                   &LY[1][lg * 4 + r][32 * w + 16 * t + lr]);
                }
            }
        }
        __syncthreads();
        float flag = -1.0f;
        {   // AF P2
            short8 yh0 = *reinterpret_cast<const short8*>(&AY[0][lr][lg * 8]);
            short8 yh1 = *reinterpret_cast<const short8*>(&AY[0][lr][32 + lg * 8]);
            short8 yl0, yl1;
            if (mode >= 1) {
                yl0 = *reinterpret_cast<const short8*>(&AY[1][lr][lg * 8]);
                yl1 = *reinterpret_cast<const short8*>(&AY[1][lr][32 + lg * 8]);
            }
            #pragma unroll
            for (int t = 0; t < 2; ++t) {
                f32x4 bH = {0.f,0.f,0.f,0.f}, bL = bH;
                bH = __builtin_amdgcn_mfma_f32_16x16x32_bf16(yh0, BtH[t][0], bH, 0, 0, 0);
                bH = __builtin_amdgcn_mfma_f32_16x16x32_bf16(yh1, BtH[t][1], bH, 0, 0, 0);
                if (mode >= 1) {
                    bL = __builtin_amdgcn_mfma_f32_16x16x32_bf16(yl0, BtH[t][0], bL, 0, 0, 0);
                    bL = __builtin_amdgcn_mfma_f32_16x16x32_bf16(yl1, BtH[t][1], bL, 0, 0, 0);
                }
                if (mode == 2) {
                    bL = __builtin_amdgcn_mfma_f32_16x16x32_bf16(yh0, BtL[t][0], bL, 0, 0, 0);
                    bL = __builtin_amdgcn_mfma_f32_16x16x32_bf16(yh1, BtL[t][1], bL, 0, 0, 0);
                }
                #pragma unroll
                for (int r = 0; r < 4; ++r) {
                    float v = atv[t] * frcp(bH[r] + bL[r] + 1.0f);
                    if (check) {
                        float p = prevA[t][r];
                        flag = fmaxf(flag, fabsf(v - p) - tol * (p + 1e-5f));
                    }
                    prevA[t][r] = v;
                    if (mode == 0) AX[0][lg * 4 + r][32 * w + 16 * t + lr] = bf16r(v);
                    else splitw(v, &AX[0][lg * 4 + r][32 * w + 16 * t + lr],
                                   &AX[1][lg * 4 + r][32 * w + 16 * t + lr]);
                }
            }
        }
        {   // LF P2
            f32x4 aH = {0.f,0.f,0.f,0.f}, aL = aH;
            #pragma unroll
            for (int ks = 0; ks < 4; ++ks) {
                short8 hi = *reinterpret_cast<const short8*>(&LY[0][lr][ks * 32 + lg * 8]);
                aH = __builtin_amdgcn_mfma_f32_16x16x32_bf16(hi, BkH[ks], aH, 0, 0, 0);
                if (mode >= 1) {
                    short8 lo = *reinterpret_cast<const short8*>(&LY[1][lr][ks * 32 + lg * 8]);
                    aL = __builtin_amdgcn_mfma_f32_16x16x32_bf16(lo, BkH[ks], aL, 0, 0, 0);
                }
                if (mode == 2)
                    aL = __builtin_amdgcn_mfma_f32_16x16x32_bf16(hi, BkL[ks], aL, 0, 0, 0);
            }
            #pragma unroll
            for (int r = 0; r < 4; ++r) {
                float v = ltv[r] * frcp(aH[r] + aL[r] + 1.0f);
                if (check) {
                    float p = prevL[r];
                    flag = fmaxf(flag, fabsf(v - p) - tol * (p + 1e-5f));
                }
                prevL[r] = v;
                if (mode == 0) LX[0][lg * 4 + r][16 * w + lr] = bf16r(v);
                else splitw(v, &LX[0][lg * 4 + r][16 * w + lr],
                               &LX[1][lg * 4 + r][16 * w + lr]);
            }
        }
        if (check) {
            #pragma unroll
            for (int off = 32; off; off >>= 1)
                flag = fmaxf(flag, __shfl_xor(flag, off));
            if (lane == 0) wred[w] = flag;
        }
        __syncthreads();
        if (check)
            done = fmaxf(fmaxf(wred[0], wred[1]), fmaxf(wred[2], wred[3])) < 0.0f;
    };

    int step = 0;
    const int cheapN = max_step < 12 ? max_step : 12;
    for (int s = 0; s < cheapN; ++s, ++step)
        iterate(IC<0>{}, false, 0.f);
    const int capC = max_step < 64 ? max_step : 64;
    while (step < capC && !done) { iterate(IC<0>{}, true, 6e-3f); ++step; }
    done = false;
    while (step < max_step && !done) { iterate(IC<1>{}, true, 5e-5f); ++step; }
    iterate(IC<2>{}, false, 0.f);
    iterate(IC<2>{}, false, 0.f);
    iterate(IC<2>{}, false, 0.f);

    #pragma unroll
    for (int t = 0; t < 2; ++t)
        #pragma unroll
        for (int r = 0; r < 4; ++r)
            AFout[(size_t)(b0row + lg * 4 + r) * NH + 32 * w + 16 * t + lr] = prevA[t][r];
    #pragma unroll
    for (int r = 0; r < 4; ++r)
        LFout[(size_t)(b0row + lg * 4 + r) * DIN + 16 * w + lr] = prevL[r];
}

// ---------------------------------------------------------------------------
// Kernel B (v11, round 17 EXACT — the validated optimum): 64-row tile,
// 2 blocks/CU, 3-buffer / 2-tiles-slack pipeline, co-residency o-tile remap
// (blocks i and i+256 share the o-tile -> trailing block's W stream hits L1).
// Depth>3 failed three ways (r11 spill-corruption, r15 crash, r18 L2-thrash
// FETCH 16.5->54MB); tile>64 rows regressed (r16). This is the plateau.
// ---------------------------------------------------------------------------
__global__ __launch_bounds__(256, 2)
void out_gemm_rank1(const float* __restrict__ AFw, const float* __restrict__ LFw,
                    const ushort* __restrict__ WT2, const float* __restrict__ bg,
                    float* __restrict__ out)
{
    __shared__ __align__(16) ushort AFb[64][136];
    __shared__ __align__(16) float  LFt[64][68];

    const int t = threadIdx.x;
    const int ot = (blockIdx.x & 255) >> 5;
    const int b0 = ((blockIdx.x >> 8) * 32 + (blockIdx.x & 31)) * 64;
    const int o0 = ot * 64;
    const int w = t >> 6, l = t & 63;
    const int lr = l & 15, lg = l >> 4;

    {
        const int row = t >> 2, q = t & 3;
        const float4* srcA = reinterpret_cast<const float4*>(
            &AFw[(size_t)(b0 + row) * NH + q * 32]);
        #pragma unroll
        for (int g = 0; g < 4; ++g) {
            float4 fa = srcA[2 * g], fb = srcA[2 * g + 1];
            uint4 wv;
            wv.x = bf16pair(fa.x, fa.y); wv.y = bf16pair(fa.z, fa.w);
            wv.z = bf16pair(fb.x, fb.y); wv.w = bf16pair(fb.z, fb.w);
            *reinterpret_cast<uint4*>(&AFb[row][q * 32 + g * 8]) = wv;
        }
        const f32x4* srcL = reinterpret_cast<const f32x4*>(
            &LFw[(size_t)(b0 + row) * DIN + q * 16]);
        #pragma unroll
        for (int g = 0; g < 4; ++g) {
            f32x4 fv = srcL[g];
            #pragma unroll
            for (int j = 0; j < 4; ++j)
                LFt[q * 16 + g * 4 + j][row] = fv[j];
        }
    }
    __syncthreads();

    const char* base = reinterpret_cast<const char*>(WT2)
        + ((size_t)(ot * 65) * 16) * 1024 + w * 4096 + l * 16;

    u32x4 bf0[4], bf1[4], bf2[4];
    ISSUE_SLICE(bf0, base);                      // T0
    ISSUE_SLICE(bf1, base + 16384);              // T1
    ISSUE_SLICE(bf2, base + 2 * 16384);          // T2

    short8 afr[4][4];
    #pragma unroll
    for (int m = 0; m < 4; ++m)
        #pragma unroll
        for (int ks = 0; ks < 4; ++ks)
            afr[m][ks] = *reinterpret_cast<const short8*>(
                &AFb[m * 16 + lr][ks * 32 + lg * 8]);

    f32x4 acc[4], tt[4];
    #pragma unroll
    for (int m = 0; m < 4; ++m) acc[m] = (f32x4){0.f, 0.f, 0.f, 0.f};

    auto computeI = [&](const u32x4* bf) {
        #pragma unroll
        for (int m = 0; m < 4; ++m) tt[m] = (f32x4){0.f, 0.f, 0.f, 0.f};
        __builtin_amdgcn_s_setprio(1);
        #pragma unroll
        for (int ks = 0; ks < 4; ++ks) {
            short8 bv = as_s8(bf[ks]);
            #pragma unroll
            for (int m = 0; m < 4; ++m)
                tt[m] = __builtin_amdgcn_mfma_f32_16x16x32_bf16(afr[m][ks], bv, tt[m], 0, 0, 0);
        }
        __builtin_amdgcn_s_setprio(0);
    };
    auto scaleAdd = [&](int i) {
        #pragma unroll
        for (int m = 0; m < 4; ++m) {
            f32x4 lf = *reinterpret_cast<const f32x4*>(&LFt[i][m * 16 + lg * 4]);
            #pragma unroll
            for (int r = 0; r < 4; ++r)
                acc[m][r] += lf[r] * tt[m][r];
        }
    };

    #pragma unroll 1
    for (int i = 0; i < 60; i += 3) {
        const char* p = base + (size_t)(i + 3) * 16384;
        WAIT_VM(8); computeI(bf0); scaleAdd(i);     ISSUE_SLICE(bf0, p);
        WAIT_VM(8); computeI(bf1); scaleAdd(i + 1); ISSUE_SLICE(bf1, p + 16384);
        WAIT_VM(8); computeI(bf2); scaleAdd(i + 2); ISSUE_SLICE(bf2, p + 2 * 16384);
    }
    WAIT_VM(8); computeI(bf0); scaleAdd(60); ISSUE_SLICE(bf0, base + (size_t)63 * 16384);
    WAIT_VM(8); computeI(bf1); scaleAdd(61); ISSUE_SLICE(bf1, base + (size_t)64 * 16384);
    WAIT_VM(8); computeI(bf2); scaleAdd(62);
    WAIT_VM(4); computeI(bf0); scaleAdd(63);
    WAIT_VM(0); computeI(bf1);                   // T64: e-term, scale 1
    #pragma unroll
    for (int m = 0; m < 4; ++m)
        #pragma unroll
        for (int r = 0; r < 4; ++r)
            acc[m][r] += tt[m][r];

    const int col = o0 + w * 16 + lr;
    const float bb = bg[col];
    #pragma unroll
    for (int m = 0; m < 4; ++m) {
        #pragma unroll
        for (int r = 0; r < 4; ++r) {
            const int row = b0 + m * 16 + lg * 4 + r;
            out[(size_t)row * DOUT + col] = acc[m][r] + bb;
        }
    }
}

// ---------------------------------------------------------------------------
// Workspace layout (bytes):
//   [0,        2097152)   AF  : float[4096][128]
//   [2097152,  3145728)   LF  : float[4096][64]
//   [3145728, +8519680)   WT2 : fragment-ordered bf16 W (8 o-tiles x 65 x 16KB)
// Fully rewritten before use each launch -> deterministic.
// ---------------------------------------------------------------------------
extern "C" void kernel_launch(void* const* d_in, const int* in_sizes, int n_in,
                              void* d_out, int out_size, void* d_ws, size_t ws_size,
                              hipStream_t stream)
{
    const float* LT   = (const float*)d_in[0];
    const float* Kg   = (const float*)d_in[1];
    const float* AT   = (const float*)d_in[2];
    const float* ug   = (const float*)d_in[3];
    const float* eg   = (const float*)d_in[4];
    const float* bg   = (const float*)d_in[5];
    const int*   msp  = (const int*)d_in[6];
    float* out = (float*)d_out;

    char* ws = (char*)d_ws;
    float*  AFw = (float*)(ws);
    float*  LFw = (float*)(ws + 2097152);
    ushort* WT2 = (ushort*)(ws + 3145728);

    // fused: 256 solve blocks + 520 prep blocks (prep hides under solve)
    solve_prep<<<dim3(NBS + 520), dim3(256), 0, stream>>>(
        LT, Kg, AT, msp, ug, eg, AFw, LFw, WT2);

    out_gemm_rank1<<<dim3(512), dim3(256), 0, stream>>>(AFw, LFw, WT2, bg, out);
}